// Round 7
// baseline (1151.193 us; speedup 1.0000x reference)
//
#include <hip/hip_runtime.h>
#include <hip/hip_fp16.h>

// LR Coulomb: per-atom neighbor sum of q_i*q_j/d * (1 - fc(d)), segment-summed
// into per-molecule bins. fc = smooth exponential cutoff at RC=4.6.
//
// R6 analysis: divergent L2 gathers are service-rate-bound (~195 G req/s;
// insensitive to MLP x2, L1 bypass, request size). Escape: tile the packed
// atom table into LDS (14 tiles x 14336 atoms x 8B = 112KB) and re-stream
// nbmat once per tile (14 x 102MB = 1.43GB, L3-resident since nbmat fits the
// 256MB L3). Per wave: ballot-compact in-tile entries into an LDS queue so
// the pair math runs exactly once per pair; gathers become ds_read_b64.
// NOTE: no nontemporal on nbmat here -- L3 retention is the whole point.

#define FACTOR 7.199822675975445f
#define RC2    (4.6f * 4.6f)

#define TILE   14336            // atoms per LDS tile (112KB of uint2)
#define WPB    8                // waves per block
#define TPB    (WPB * 64)       // 512 threads
#define QCAP   256              // per-wave queue capacity (mean ~73, 22 sigma)

typedef int v4i __attribute__((ext_vector_type(4)));

// Fused: zero output bins + pack (x,y,z,q) -> 4 x fp16 in 8 bytes.
__global__ void prep_kernel(const float* __restrict__ coord,
                            const float* __restrict__ charges,
                            uint2* __restrict__ tbl, int n1,
                            float* __restrict__ out, int nout) {
    int i = blockIdx.x * blockDim.x + threadIdx.x;
    if (i < nout) out[i] = 0.0f;
    if (i < n1) {
        unsigned hx = __half_as_ushort(__float2half_rn(coord[3 * i + 0]));
        unsigned hy = __half_as_ushort(__float2half_rn(coord[3 * i + 1]));
        unsigned hz = __half_as_ushort(__float2half_rn(coord[3 * i + 2]));
        unsigned hq = __half_as_ushort(__float2half_rn(charges[i]));
        tbl[i] = make_uint2(hx | (hy << 16), hz | (hq << 16));
    }
}

__device__ __forceinline__ float4 unpack_h4(uint2 p) {
    unsigned px = p.x, py = p.y;
    __half2 a = *reinterpret_cast<__half2*>(&px);
    __half2 b = *reinterpret_cast<__half2*>(&py);
    float2 fa = __half22float2(a);
    float2 fb = __half22float2(b);
    return make_float4(fa.x, fa.y, fb.x, fb.y);
}

__global__ __launch_bounds__(TPB) void coulomb_tiled(
    const uint2* __restrict__ tbl,      // (N+1) packed half4 records
    const int*   __restrict__ nbmat,    // N*M row-major
    const int*   __restrict__ mol_idx,  // N (sorted)
    float*       __restrict__ out,      // N_MOL
    int N, int n1, int M, int rows_per_blk)
{
    __shared__ uint2    tile[TILE];           // 114688 B
    __shared__ unsigned queue[WPB][QCAP];     //   8192 B
    __shared__ uint2    centers[WPB][8];      //    512 B
    __shared__ float    rowacc[WPB][8];       //    256 B

    // --- load this block's table tile (read-only for block lifetime) ---
    const int tb = blockIdx.y * TILE;
    for (int k = threadIdx.x; k < TILE; k += TPB) {
        int src = tb + k;
        if (src >= n1) src = n1 - 1;            // clamp; never queued anyway
        tile[k] = tbl[src];
    }
    __syncthreads();

    const int wave = threadIdx.x >> 6;
    const int lane = threadIdx.x & 63;
    const int half = lane >> 5;
    const unsigned long long lm = (1ull << lane) - 1ull;

    const int rstart = blockIdx.x * rows_per_blk;
    const int rend   = min(rstart + rows_per_blk, N);

    if (lane < 8) rowacc[wave][lane] = 0.0f;

    // --- each wave: 8 rows per stint, strided by block's 64 rows ---
    for (int R = rstart + wave * 8; R < rend; R += WPB * 8) {
        // centers for rows R..R+7 (clamped; invalid rows masked by pred)
        if (lane < 8) {
            int ia = R + lane; if (ia > N - 1) ia = N - 1;
            centers[wave][lane] = tbl[ia];
        }

        // nbmat: chunk c covers rows {R+2c, R+2c+1} = 1KB; lane reads 16B.
        // Plain loads (cache in L2/L3 -- re-read by other tiles' blocks).
        v4i jv[4];
        #pragma unroll
        for (int c = 0; c < 4; ++c) {
            int rc = R + 2 * c; if (rc > N - 2) rc = N - 2;
            const v4i* rowp = reinterpret_cast<const v4i*>(
                nbmat + (size_t)rc * M);
            jv[c] = rowp[lane];
        }

        // --- ballot-compact in-tile entries into this wave's LDS queue ---
        int qtot = 0;
        #pragma unroll
        for (int c = 0; c < 4; ++c) {
            #pragma unroll
            for (int e = 0; e < 4; ++e) {
                const int j = (e == 0) ? jv[c].x : (e == 1) ? jv[c].y
                            : (e == 2) ? jv[c].z : jv[c].w;
                const int row  = 2 * c + half;
                const int irow = R + row;
                const unsigned jl = (unsigned)(j - tb);
                const bool pred = (jl < (unsigned)TILE) & (j != N)
                                & (j != irow) & (irow < rend);
                const unsigned long long mk = __ballot(pred);
                if (pred) {
                    int rk = qtot + (int)__popcll(mk & lm);
                    if (rk < QCAP)
                        queue[wave][rk] = jl | ((unsigned)row << 14);
                }
                qtot += (int)__popcll(mk);
            }
        }
        if (qtot > QCAP) qtot = QCAP;

        // --- dense math over the queue: gathers served by LDS ---
        for (int qb = 0; qb < qtot; qb += 64) {
            const int idx = qb + lane;
            const bool act = idx < qtot;
            const unsigned rec = queue[wave][act ? idx : 0];
            unsigned jl = rec & 0x3FFFu; if (jl >= (unsigned)TILE) jl = 0;
            const int row = (rec >> 14) & 7;
            const float4 nb = unpack_h4(tile[jl]);
            const float4 me = unpack_h4(centers[wave][row]);
            const float dx = me.x - nb.x, dy = me.y - nb.y, dz = me.z - nb.z;
            const float d2 = dx * dx + dy * dy + dz * dz;
            float inner = fmaxf(1.0f - d2 * (1.0f / RC2), 1e-12f);
            const float fcf = (d2 < RC2) ? __expf(1.0f - 1.0f / inner) : 0.0f;
            float term = (me.w * nb.w) * rsqrtf(d2) * (1.0f - fcf);
            term = act ? term : 0.0f;
            atomicAdd(&rowacc[wave][row], term);   // ds_add_f32
        }

        // --- flush: 8 lanes in parallel, one atomic per (row, tile) ---
        if (lane < 8) {
            const int ia = R + lane;
            if (ia < rend) {
                const float v = rowacc[wave][lane];
                if (v != 0.0f) atomicAdd(&out[mol_idx[ia]], FACTOR * v);
                rowacc[wave][lane] = 0.0f;
            }
        }
    }
}

// Fallback (ws too small for the packed table): single-pass L2-gather kernel.
__global__ __launch_bounds__(256) void coulomb_fallback(
    const float* __restrict__ coord,
    const float* __restrict__ charges,
    const int*   __restrict__ nbmat,
    const int*   __restrict__ mol_idx,
    float*       __restrict__ out,
    int N, int Mhalf)
{
    const int wave = threadIdx.x >> 6;
    const int lane = threadIdx.x & 63;
    const int i = blockIdx.x * 4 + wave;
    if (i >= N) return;

    const float xi = coord[3 * i + 0];
    const float yi = coord[3 * i + 1];
    const float zi = coord[3 * i + 2];
    const float qi = charges[i];

    const long long packed = reinterpret_cast<const long long*>(
        nbmat)[(size_t)i * Mhalf + lane];
    const int j0 = (int)(packed & 0xffffffffLL);
    const int j1 = (int)(packed >> 32);

    float sum = 0.0f;
    #pragma unroll
    for (int k = 0; k < 2; ++k) {
        const int j = (k == 0) ? j0 : j1;
        const bool valid = (j != N) && (j != i);
        const float dx = xi - coord[3 * j + 0];
        const float dy = yi - coord[3 * j + 1];
        const float dz = zi - coord[3 * j + 2];
        const float d2 = dx * dx + dy * dy + dz * dz;
        float inner = fmaxf(1.0f - d2 * (1.0f / RC2), 1e-12f);
        const float fc = (d2 < RC2) ? __expf(1.0f - 1.0f / inner) : 0.0f;
        const float term = (qi * charges[j]) * rsqrtf(d2) * (1.0f - fc);
        sum += valid ? term : 0.0f;
    }
    #pragma unroll
    for (int off = 32; off > 0; off >>= 1)
        sum += __shfl_down(sum, off, 64);
    if (lane == 0) atomicAdd(&out[mol_idx[i]], FACTOR * sum);
}

__global__ void zero_out_kernel(float* __restrict__ out, int n) {
    int i = blockIdx.x * blockDim.x + threadIdx.x;
    if (i < n) out[i] = 0.0f;
}

extern "C" void kernel_launch(void* const* d_in, const int* in_sizes, int n_in,
                              void* d_out, int out_size, void* d_ws, size_t ws_size,
                              hipStream_t stream) {
    const float* coord   = (const float*)d_in[0];
    const float* charges = (const float*)d_in[1];
    const int*   nbmat   = (const int*)d_in[2];
    const int*   mol_idx = (const int*)d_in[3];
    float* out = (float*)d_out;

    const int N  = in_sizes[3];          // 200000
    const int n1 = in_sizes[1];          // N+1
    const int M  = in_sizes[2] / N;      // 128

    if (ws_size >= (size_t)n1 * sizeof(uint2)) {
        uint2* tbl = (uint2*)d_ws;
        const int prep_n = (n1 > out_size) ? n1 : out_size;
        prep_kernel<<<(prep_n + 255) / 256, 256, 0, stream>>>(
            coord, charges, tbl, n1, out, out_size);

        const int ntiles = (n1 + TILE - 1) / TILE;           // 14
        int K = (512 + ntiles - 1) / ntiles;                 // ~37 row-parts
        if (K < 1) K = 1;
        const int rows_per_blk = (N + K - 1) / K;
        dim3 grid(K, ntiles);
        coulomb_tiled<<<grid, TPB, 0, stream>>>(tbl, nbmat, mol_idx, out,
                                                N, n1, M, rows_per_blk);
    } else {
        zero_out_kernel<<<(out_size + 255) / 256, 256, 0, stream>>>(out, out_size);
        coulomb_fallback<<<(N + 3) / 4, 256, 0, stream>>>(
            coord, charges, nbmat, mol_idx, out, N, M / 2);
    }
}

// Round 8
// 129.838 us; speedup vs baseline: 8.8664x; 8.8664x over previous
//
#include <hip/hip_runtime.h>
#include <hip/hip_fp16.h>

// LR Coulomb: per-atom neighbor sum of q_i*q_j/d * (1 - fc(d)), segment-summed
// into per-molecule bins. fc is the smooth exponential cutoff at RC=4.6.
//
// Final structure (R5 revert + launch fusion). Evidence trail:
//  R2: float4 packing (4 dword gathers -> 1 dwordx4)   365 -> 265 us
//  R3: 4 atoms/wave (2x in-flight gathers)              265 -> 136 us
//  R5: 8 atoms/wave + fp16 records (8B gathers)         136 -> 128 us
//  R6: L1-bypass sc0 gathers                            null (132 us)
//  R7: LDS-tiled table + nbmat re-stream                1151 us (L3 thrash)
// Conclusion: bound by L2 random-gather service (~200 G req/s, ~64% of the
// ideal 16 chan/XCD rate). 25.6M 8B gathers ~ 83 us floor + nbmat stream.

#define FACTOR 7.199822675975445f
#define RC2    (4.6f * 4.6f)
#define ATOMS  8                 // per wave (2 per chunk x 4 chunks)

typedef int v4i __attribute__((ext_vector_type(4)));

// Fused: zero output bins + pack (x,y,z,q) -> 4 x fp16 in 8 bytes.
__global__ void prep_kernel(const float* __restrict__ coord,
                            const float* __restrict__ charges,
                            uint2* __restrict__ tbl, int n1,
                            float* __restrict__ out, int nout) {
    int i = blockIdx.x * blockDim.x + threadIdx.x;
    if (i < nout) out[i] = 0.0f;
    if (i < n1) {
        unsigned hx = __half_as_ushort(__float2half_rn(coord[3 * i + 0]));
        unsigned hy = __half_as_ushort(__float2half_rn(coord[3 * i + 1]));
        unsigned hz = __half_as_ushort(__float2half_rn(coord[3 * i + 2]));
        unsigned hq = __half_as_ushort(__float2half_rn(charges[i]));
        tbl[i] = make_uint2(hx | (hy << 16), hz | (hq << 16));
    }
}

__device__ __forceinline__ float4 unpack_h4(uint2 p) {
    unsigned px = p.x, py = p.y;
    __half2 a = *reinterpret_cast<__half2*>(&px);
    __half2 b = *reinterpret_cast<__half2*>(&py);
    float2 fa = __half22float2(a);
    float2 fb = __half22float2(b);
    return make_float4(fa.x, fa.y, fb.x, fb.y);
}

__global__ __launch_bounds__(256) void coulomb_kernel(
    const uint2* __restrict__ tbl,      // (N+1) packed half4 records
    const int*   __restrict__ nbmat,    // N*M row-major
    const int*   __restrict__ mol_idx,  // N (sorted)
    float*       __restrict__ out,      // N_MOL
    int N8, int N, int M)               // N8 = N rounded down to ATOMS
{
    const int wave = threadIdx.x >> 6;
    const int lane = threadIdx.x & 63;
    const int half = lane >> 5;         // which row of the chunk's 2 rows
    const int base = (blockIdx.x * 4 + wave) * ATOMS;
    if (base >= N8) return;

    // --- centers: 4 chunks x 2 rows; lane needs atom (base+2c+half) ---
    uint2 mep[4];
    #pragma unroll
    for (int c = 0; c < 4; ++c)
        mep[c] = tbl[base + 2 * c + half];

    // --- nbmat: chunk c covers rows {base+2c, base+2c+1} = 256 ints = 1KB.
    //     lane reads int4 at 16B*lane (lanes 0-31 -> row0, 32-63 -> row1).
    //     Streamed exactly once -> nontemporal (don't pollute L2).
    v4i jv[4];
    #pragma unroll
    for (int c = 0; c < 4; ++c) {
        const v4i* rowp = reinterpret_cast<const v4i*>(
            nbmat + (size_t)(base + 2 * c) * M);
        jv[c] = __builtin_nontemporal_load(rowp + lane);
    }

    // --- 16 divergent 8B gathers, all issued before compute; compiler
    //     schedules counted vmcnt waits per consuming chunk (R6 showed
    //     forced vmcnt(0) is no better). Table is L2-resident per XCD. ---
    uint2 nbp[4][4];
    #pragma unroll
    for (int c = 0; c < 4; ++c) {
        nbp[c][0] = tbl[jv[c].x];
        nbp[c][1] = tbl[jv[c].y];
        nbp[c][2] = tbl[jv[c].z];
        nbp[c][3] = tbl[jv[c].w];
    }

    // --- compute ---
    float sums[4];
    #pragma unroll
    for (int c = 0; c < 4; ++c) {
        const int i = base + 2 * c + half;
        const float4 me = unpack_h4(mep[c]);
        float s = 0.0f;
        const int jj[4] = {jv[c].x, jv[c].y, jv[c].z, jv[c].w};
        #pragma unroll
        for (int k = 0; k < 4; ++k) {
            const int j = jj[k];
            const bool valid = (j != N) && (j != i);
            const float4 nb = unpack_h4(nbp[c][k]);
            const float dx = me.x - nb.x;
            const float dy = me.y - nb.y;
            const float dz = me.z - nb.z;
            const float d2 = dx * dx + dy * dy + dz * dz;
            float inner = fmaxf(1.0f - d2 * (1.0f / RC2), 1e-12f);
            const float fc = (d2 < RC2) ? __expf(1.0f - 1.0f / inner) : 0.0f;
            const float term = (me.w * nb.w) * rsqrtf(d2) * (1.0f - fc);
            s += valid ? term : 0.0f;
        }
        sums[c] = s;
    }

    // --- reduce within each 32-lane half (xor offsets stay inside half) ---
    #pragma unroll
    for (int off = 16; off > 0; off >>= 1) {
        #pragma unroll
        for (int c = 0; c < 4; ++c)
            sums[c] += __shfl_xor(sums[c], off, 64);
    }

    // --- lanes 0 and 32 own atoms {base+2c+half}; merge same-molecule bins ---
    if ((lane & 31) == 0) {
        float acc = 0.0f;
        int cur = -1;
        #pragma unroll
        for (int c = 0; c < 4; ++c) {
            const int ia = base + 2 * c + half;
            const int ma = mol_idx[ia];
            if (ma != cur) {
                if (cur >= 0) atomicAdd(&out[cur], FACTOR * acc);
                cur = ma;
                acc = 0.0f;
            }
            acc += sums[c];
        }
        if (cur >= 0) atomicAdd(&out[cur], FACTOR * acc);
    }
}

// Tail: one wave per atom for the N%ATOMS remainder (unused at N=200000).
__global__ __launch_bounds__(256) void coulomb_tail_kernel(
    const uint2* __restrict__ tbl,
    const int*   __restrict__ nbmat,
    const int*   __restrict__ mol_idx,
    float*       __restrict__ out,
    int start, int N, int Mhalf)
{
    const int wave = threadIdx.x >> 6;
    const int lane = threadIdx.x & 63;
    const int i = start + blockIdx.x * 4 + wave;
    if (i >= N) return;

    const float4 me = unpack_h4(tbl[i]);
    const long long packed = __builtin_nontemporal_load(
        reinterpret_cast<const long long*>(nbmat) + (size_t)i * Mhalf + lane);
    const int j0 = (int)(packed & 0xffffffffLL);
    const int j1 = (int)(packed >> 32);

    float sum = 0.0f;
    #pragma unroll
    for (int k = 0; k < 2; ++k) {
        const int j = (k == 0) ? j0 : j1;
        const bool valid = (j != N) && (j != i);
        const float4 nb = unpack_h4(tbl[j]);
        const float dx = me.x - nb.x, dy = me.y - nb.y, dz = me.z - nb.z;
        const float d2 = dx * dx + dy * dy + dz * dz;
        float inner = fmaxf(1.0f - d2 * (1.0f / RC2), 1e-12f);
        const float fc = (d2 < RC2) ? __expf(1.0f - 1.0f / inner) : 0.0f;
        const float term = (me.w * nb.w) * rsqrtf(d2) * (1.0f - fc);
        sum += valid ? term : 0.0f;
    }
    #pragma unroll
    for (int off = 32; off > 0; off >>= 1)
        sum += __shfl_down(sum, off, 64);
    if (lane == 0) atomicAdd(&out[mol_idx[i]], FACTOR * sum);
}

extern "C" void kernel_launch(void* const* d_in, const int* in_sizes, int n_in,
                              void* d_out, int out_size, void* d_ws, size_t ws_size,
                              hipStream_t stream) {
    const float* coord   = (const float*)d_in[0];
    const float* charges = (const float*)d_in[1];
    const int*   nbmat   = (const int*)d_in[2];
    const int*   mol_idx = (const int*)d_in[3];
    float* out = (float*)d_out;

    const int N  = in_sizes[3];         // 200000
    const int n1 = in_sizes[1];         // N+1
    const int M  = in_sizes[2] / N;     // 128

    uint2* tbl = (uint2*)d_ws;          // n1 * 8 bytes
    const int prep_n = (n1 > out_size) ? n1 : out_size;
    prep_kernel<<<(prep_n + 255) / 256, 256, 0, stream>>>(
        coord, charges, tbl, n1, out, out_size);

    const int N8 = N - (N % ATOMS);
    const int blocks = (N8 + 4 * ATOMS - 1) / (4 * ATOMS);
    coulomb_kernel<<<blocks, 256, 0, stream>>>(tbl, nbmat, mol_idx, out,
                                               N8, N, M);
    const int rem = N - N8;
    if (rem > 0) {
        coulomb_tail_kernel<<<(rem + 3) / 4, 256, 0, stream>>>(
            tbl, nbmat, mol_idx, out, N8, N, M / 2);
    }
}